// Round 5
// baseline (1193.199 us; speedup 1.0000x reference)
//
#include <hip/hip_runtime.h>
#include <math.h>

#define NN 100000
#define NE 3200000
#define NG 512
#define SCAN_BLOCK 256
#define SCAN_ELEMS 1024
#define NBLK ((NN + SCAN_ELEMS - 1) / SCAN_ELEMS)
#define BSHIFT 5
#define NBUCK ((NN + 31) >> 5)   // 3125, dst-aligned 32-node buckets

// ---------------- zero deg + bucket cursors ----------------
__global__ void zero_all_kernel(int* deg, int* bcur, int n, int nb) {
    int i = blockIdx.x * blockDim.x + threadIdx.x;
    if (i < n) deg[i] = 0;
    if (i < nb) bcur[i] = 0;
}

__global__ void zero_pool_kernel(float* p, int n) {
    int i = blockIdx.x * blockDim.x + threadIdx.x;
    if (i < n) p[i] = 0.f;
}

// ---------------- int degree histogram over dst ----------------
__global__ void deg_count_kernel(const int* __restrict__ dst, int* deg, int e) {
    int i = blockIdx.x * blockDim.x + threadIdx.x;
    if (i < e) atomicAdd(&deg[dst[i]], 1);
}

// ---------------- dinv = rsqrt(deg_edges + 1)  (self-loop) ----------------
__global__ void dinv_kernel(const int* __restrict__ deg, float* dinv, int n) {
    int i = blockIdx.x * blockDim.x + threadIdx.x;
    if (i < n) dinv[i] = rsqrtf((float)(deg[i] + 1));
}

// ---------------- scan pass 1 ----------------
__global__ void scan1_kernel(const int* __restrict__ deg, int* __restrict__ rowptr,
                             int* __restrict__ bsums, int n) {
    __shared__ int lds[SCAN_BLOCK];
    int base = blockIdx.x * SCAN_ELEMS;
    int t = threadIdx.x;
    int v[4];
    int s = 0;
#pragma unroll
    for (int j = 0; j < 4; j++) {
        int i = base + t * 4 + j;
        v[j] = (i < n) ? deg[i] : 0;
        s += v[j];
    }
    lds[t] = s;
    __syncthreads();
    for (int off = 1; off < SCAN_BLOCK; off <<= 1) {
        int val = (t >= off) ? lds[t - off] : 0;
        __syncthreads();
        lds[t] += val;
        __syncthreads();
    }
    int run = (t > 0) ? lds[t - 1] : 0;
    if (t == SCAN_BLOCK - 1) bsums[blockIdx.x] = lds[t];
#pragma unroll
    for (int j = 0; j < 4; j++) {
        int i = base + t * 4 + j;
        run += v[j];
        if (i < n) rowptr[i + 1] = run;
    }
}

// ---------------- scan pass 2 ----------------
__global__ void scan2_kernel(int* bsums, int nb) {
    if (threadIdx.x == 0 && blockIdx.x == 0) {
        int acc = 0;
        for (int b = 0; b < nb; b++) { int v = bsums[b]; bsums[b] = acc; acc += v; }
    }
}

// ---------------- scan pass 3 ----------------
__global__ void scan3_kernel(int* rowptr, const int* __restrict__ bsums, int n) {
    int i = blockIdx.x * blockDim.x + threadIdx.x;
    if (i == 0) rowptr[0] = 0;
    if (i < n) rowptr[i + 1] += bsums[i / SCAN_ELEMS];
}

// ---------------- bucket phase A: scatter (src,dst) to dst-aligned buckets ----------------
__global__ void bucketA_kernel(const int* __restrict__ src, const int* __restrict__ dst,
                               const int* __restrict__ rowptr, int* bcur,
                               int2* __restrict__ temp, int e) {
    int i = blockIdx.x * blockDim.x + threadIdx.x;
    if (i >= e) return;
    int s = src[i];
    int d = dst[i];
    int b = d >> BSHIFT;
    int base = rowptr[b << BSHIFT];     // bucket base slot (L2-hot table)
    int pos = atomicAdd(&bcur[b], 1);
    int2 v; v.x = s; v.y = d;
    temp[base + pos] = v;
}

// ---------------- bucket phase B: reorder bucket into exact CSR slots ----------------
__global__ __launch_bounds__(256) void bucketB_kernel(const int2* __restrict__ temp,
                                                      const int* __restrict__ rowptr,
                                                      int* __restrict__ csr_src, int n) {
    __shared__ int cur[32];
    __shared__ int rp[33];
    int b = blockIdx.x;
    int d0 = b << BSHIFT;
    int t = threadIdx.x;
    if (t < 32) { cur[t] = 0; rp[t] = rowptr[min(d0 + t, n)]; }
    if (t == 32) rp[32] = rowptr[min(d0 + 32, n)];
    __syncthreads();
    int lo = rp[0], hi = rp[32];
    for (int i = lo + t; i < hi; i += 256) {
        int2 e = temp[i];
        int ld = e.y - d0;
        int slot = rp[ld] + atomicAdd(&cur[ld], 1);
        csr_src[slot] = e.x;
    }
}

// ---------------- t4[(kb*n+node)*8+f] = (x[n,128] @ W[128,32]) blocked ----------------
__global__ __launch_bounds__(256) void gemm128_32_tiled(
    const float* __restrict__ x, const float* __restrict__ W, float* __restrict__ t4, int n) {
    __shared__ float Wl[128 * 32];   // 16 KB
    __shared__ float Xl[64 * 132];   // 33.8 KB
    int t = threadIdx.x;
    for (int i = t; i < 128 * 32; i += 256) Wl[i] = W[i];
    int tile0 = blockIdx.x * 64;
    for (int idx = t; idx < 64 * 128; idx += 256) {
        int r = idx >> 7, k = idx & 127;
        int node = tile0 + r;
        Xl[r * 132 + k] = (node < n) ? x[(long long)node * 128 + k] : 0.f;
    }
    __syncthreads();
    int cg = t & 7, ng = t >> 3;
    int c0 = cg * 4;
    float acc[2][4];
#pragma unroll
    for (int i = 0; i < 2; i++)
        for (int j = 0; j < 4; j++) acc[i][j] = 0.f;
    for (int k = 0; k < 128; k++) {
        float4 w = *(const float4*)&Wl[k * 32 + c0];
#pragma unroll
        for (int i = 0; i < 2; i++) {
            float a = Xl[(ng * 2 + i) * 132 + k];
            acc[i][0] += a * w.x; acc[i][1] += a * w.y;
            acc[i][2] += a * w.z; acc[i][3] += a * w.w;
        }
    }
#pragma unroll
    for (int i = 0; i < 2; i++) {
        int node = tile0 + ng * 2 + i;
        if (node < n)
            *(float4*)&t4[((size_t)(c0 >> 3) * n + node) * 8 + (c0 & 7)] =
                make_float4(acc[i][0], acc[i][1], acc[i][2], acc[i][3]);
    }
}

// ---------------- t4 blocked = xin[n,32] @ W[32,32] ----------------
__global__ void gemm32_32_kernel(const float* __restrict__ xin, const float* __restrict__ W,
                                 float* __restrict__ t4, int n) {
    __shared__ float Wl[32 * 32];
    for (int i = threadIdx.x; i < 32 * 32; i += blockDim.x) Wl[i] = W[i];
    __syncthreads();
    int node = blockIdx.x * blockDim.x + threadIdx.x;
    if (node >= n) return;
    float acc[32];
#pragma unroll
    for (int k = 0; k < 32; k++) acc[k] = 0.f;
    const float4* xp = (const float4*)(xin + (long long)node * 32);
#pragma unroll
    for (int j4 = 0; j4 < 8; j4++) {
        float4 v4 = xp[j4];
        float vv[4] = {v4.x, v4.y, v4.z, v4.w};
#pragma unroll
        for (int c = 0; c < 4; c++) {
            const float* wr = &Wl[(j4 * 4 + c) * 32];
#pragma unroll
            for (int k = 0; k < 32; k++) acc[k] += vv[c] * wr[k];
        }
    }
#pragma unroll
    for (int k4 = 0; k4 < 8; k4++) {
        int c0 = k4 * 4;
        *(float4*)&t4[((size_t)(c0 >> 3) * n + node) * 8 + (c0 & 7)] =
            make_float4(acc[c0], acc[c0 + 1], acc[c0 + 2], acc[c0 + 3]);
    }
}

// ---------------- feature-blocked pull aggregation, kb = blockIdx.y ----------------
// 32 lanes/node: 4 edge-slots x 8 features. Per-pass gather table = 3.2 MB (L2-fits).
__global__ __launch_bounds__(256) void gather4_kernel(
    const int* __restrict__ rowptr, const int* __restrict__ csr_src,
    const float* __restrict__ dinv, const float* __restrict__ t4,
    const float* __restrict__ bias, float* __restrict__ xo, int n) {
    int node = blockIdx.x * 8 + (threadIdx.x >> 5);
    if (node >= n) return;
    int lane = threadIdx.x & 31;
    int sub = lane >> 3, f = lane & 7;
    int kb = blockIdx.y;
    const float* tb = t4 + (size_t)kb * n * 8;
    float dd = dinv[node];
    int beg = rowptr[node], end = rowptr[node + 1];
    float acc = 0.f;
    for (int e = beg + sub; e < end; e += 4) {
        int s = csr_src[e];
        acc += tb[s * 8 + f] * dinv[s];
    }
    acc += __shfl_xor(acc, 8, 64);
    acc += __shfl_xor(acc, 16, 64);
    if (sub == 0) {
        float self = tb[node * 8 + f] * dd;
        xo[node * 32 + kb * 8 + f] = fmaxf((acc + self) * dd + bias[kb * 8 + f], 0.f);
    }
}

// ---------------- h64 = relu(concat(x1,x2,x3) @ fc1_w + fc1_b), 64-node tiles ----------------
__global__ __launch_bounds__(256) void fc1_tiled_kernel(
    const float* __restrict__ x1, const float* __restrict__ x2, const float* __restrict__ x3,
    const float* __restrict__ W, const float* __restrict__ b, float* __restrict__ h64, int n) {
    __shared__ float Wl[96 * 64];   // 24 KB
    __shared__ float Xl[64][97];    // 24.8 KB
    int t = threadIdx.x;
    for (int i = t; i < 96 * 64; i += 256) Wl[i] = W[i];
    int tile0 = blockIdx.x * 64;
    for (int idx = t; idx < 64 * 32; idx += 256) {
        int r = idx >> 5, j = idx & 31;
        int node = tile0 + r;
        float v1 = 0.f, v2 = 0.f, v3 = 0.f;
        if (node < n) {
            v1 = x1[node * 32 + j];
            v2 = x2[node * 32 + j];
            v3 = x3[node * 32 + j];
        }
        Xl[r][j] = v1; Xl[r][32 + j] = v2; Xl[r][64 + j] = v3;
    }
    __syncthreads();
    int cg = t & 15, ng = t >> 4;
    int c0 = cg * 4;
    float4 bb = *(const float4*)&b[c0];
    float acc[4][4];
#pragma unroll
    for (int i = 0; i < 4; i++) {
        acc[i][0] = bb.x; acc[i][1] = bb.y; acc[i][2] = bb.z; acc[i][3] = bb.w;
    }
    for (int k = 0; k < 96; k++) {
        float4 w = *(const float4*)&Wl[k * 64 + c0];
#pragma unroll
        for (int i = 0; i < 4; i++) {
            float a = Xl[ng * 4 + i][k];
            acc[i][0] += a * w.x; acc[i][1] += a * w.y;
            acc[i][2] += a * w.z; acc[i][3] += a * w.w;
        }
    }
#pragma unroll
    for (int i = 0; i < 4; i++) {
        int node = tile0 + ng * 4 + i;
        if (node < n)
            *(float4*)&h64[node * 64 + c0] =
                make_float4(fmaxf(acc[i][0], 0.f), fmaxf(acc[i][1], 0.f),
                            fmaxf(acc[i][2], 0.f), fmaxf(acc[i][3], 0.f));
    }
}

// ---------------- h128 = relu(h64 @ fc2a_w + b) fused with segment pooling ----------------
__global__ __launch_bounds__(256) void fc2a_pool_kernel(
    const float* __restrict__ h64, const float* __restrict__ W, const float* __restrict__ b,
    const int* __restrict__ batch, float* __restrict__ pooled, int n) {
    __shared__ float Wl[64 * 128];  // 32 KB
    __shared__ float Al[64 * 64];   // 16 KB
    __shared__ int batchl[64];
    int t = threadIdx.x;
    for (int i = t; i < 64 * 128; i += 256) Wl[i] = W[i];
    int tile0 = blockIdx.x * 64;
    for (int idx = t; idx < 64 * 64; idx += 256) {
        int r = idx >> 6, k = idx & 63;
        int node = tile0 + r;
        Al[idx] = (node < n) ? h64[node * 64 + k] : 0.f;
    }
    if (t < 64) batchl[t] = (tile0 + t < n) ? batch[tile0 + t] : -1;
    __syncthreads();
    int cg = t & 31, ng = t >> 5;
    int c0 = cg * 4;
    float acc[8][4];
#pragma unroll
    for (int i = 0; i < 8; i++)
        for (int j = 0; j < 4; j++) acc[i][j] = 0.f;
    for (int k = 0; k < 64; k++) {
        float4 w = *(const float4*)&Wl[k * 128 + c0];
#pragma unroll
        for (int i = 0; i < 8; i++) {
            float a = Al[(ng * 8 + i) * 64 + k];
            acc[i][0] += a * w.x; acc[i][1] += a * w.y;
            acc[i][2] += a * w.z; acc[i][3] += a * w.w;
        }
    }
    float4 bb = *(const float4*)&b[c0];
    int base = ng * 8;
    if (tile0 + base < n) {
        float r0 = 0.f, r1 = 0.f, r2 = 0.f, r3 = 0.f;
        int curg = batchl[base];
        for (int i = 0; i < 8; i++) {
            int node = tile0 + base + i;
            if (node >= n) break;
            int gi = batchl[base + i];
            if (gi != curg) {
                float* dst = pooled + (long long)curg * 128 + c0;
                atomicAdd(dst + 0, r0); atomicAdd(dst + 1, r1);
                atomicAdd(dst + 2, r2); atomicAdd(dst + 3, r3);
                r0 = r1 = r2 = r3 = 0.f;
                curg = gi;
            }
            r0 += fmaxf(acc[i][0] + bb.x, 0.f);
            r1 += fmaxf(acc[i][1] + bb.y, 0.f);
            r2 += fmaxf(acc[i][2] + bb.z, 0.f);
            r3 += fmaxf(acc[i][3] + bb.w, 0.f);
        }
        float* dst = pooled + (long long)curg * 128 + c0;
        atomicAdd(dst + 0, r0); atomicAdd(dst + 1, r1);
        atomicAdd(dst + 2, r2); atomicAdd(dst + 3, r3);
    }
}

// ---------------- head: relu(pooled@fc2b+b) @ fc3 + b3 -> log_softmax ----------------
__global__ void head_kernel(const float* __restrict__ pooled, const float* __restrict__ W2b,
                            const float* __restrict__ b2b, const float* __restrict__ W3,
                            const float* __restrict__ b3, float* __restrict__ out) {
    __shared__ float Wl[128 * 64];
    for (int i = threadIdx.x; i < 128 * 64; i += blockDim.x) Wl[i] = W2b[i];
    __syncthreads();
    int g = blockIdx.x * blockDim.x + threadIdx.x;
    if (g >= NG) return;
    float acc[64];
#pragma unroll
    for (int k = 0; k < 64; k++) acc[k] = b2b[k];
    const float* p0 = pooled + (long long)g * 128;
    for (int j = 0; j < 128; j++) {
        float v = p0[j];
        const float* wr = &Wl[j * 64];
#pragma unroll
        for (int k = 0; k < 64; k++) acc[k] += v * wr[k];
    }
    float l0 = b3[0], l1 = b3[1];
#pragma unroll
    for (int k = 0; k < 64; k++) {
        float h = fmaxf(acc[k], 0.f);
        l0 += h * W3[k * 2 + 0];
        l1 += h * W3[k * 2 + 1];
    }
    float m = fmaxf(l0, l1);
    float lse = m + logf(expf(l0 - m) + expf(l1 - m));
    out[g * 2 + 0] = l0 - lse;
    out[g * 2 + 1] = l1 - lse;
}

extern "C" void kernel_launch(void* const* d_in, const int* in_sizes, int n_in,
                              void* d_out, int out_size, void* d_ws, size_t ws_size,
                              hipStream_t stream) {
    const float* x     = (const float*)d_in[0];
    const int*   ei    = (const int*)d_in[1];
    const int*   srcI  = ei;
    const int*   dstI  = ei + NE;
    const int*   batch = (const int*)d_in[2];
    const float* W1    = (const float*)d_in[3];
    const float* b1    = (const float*)d_in[4];
    const float* W2    = (const float*)d_in[5];
    const float* b2    = (const float*)d_in[6];
    const float* W3w   = (const float*)d_in[7];
    const float* b3w   = (const float*)d_in[8];
    const float* fc1w  = (const float*)d_in[9];
    const float* fc1b  = (const float*)d_in[10];
    const float* fc2aw = (const float*)d_in[11];
    const float* fc2ab = (const float*)d_in[12];
    const float* fc2bw = (const float*)d_in[13];
    const float* fc2bb = (const float*)d_in[14];
    const float* fc3w  = (const float*)d_in[15];
    const float* fc3b  = (const float*)d_in[16];
    float* out = (float*)d_out;

    // ---- workspace layout ----
    char* p = (char*)d_ws;
    int* deg_i = (int*)p;                 p += (size_t)NN * 4;
    int* rowptr = (int*)p;                p += (size_t)(NN + 4) * 4;
    int* bsums = (int*)p;                 p += 4096;
    int* bcur = (int*)p;                  p += (size_t)((NBUCK + 1024) & ~1023) * 4;
    float* dinv = (float*)p;              p += (size_t)NN * 4;
    int* csr_src = (int*)p;               p += (size_t)NE * 4;          // 12.8 MB
    float* t4 = (float*)p;                p += (size_t)NN * 32 * 4;     // 12.8 MB
    float* x1 = (float*)p;                p += (size_t)NN * 32 * 4;
    float* x2 = (float*)p;                p += (size_t)NN * 32 * 4;
    float* x3 = (float*)p;                p += (size_t)NN * 32 * 4;
    float* pooled = (float*)p;            p += (size_t)NG * 128 * 4;
    int2* temp = (int2*)x2;               // alias x2+x3 (25.6 MB, dead before layer 1)
    float* h64 = (float*)csr_src;         // alias csr_src+t4 (25.6 MB, dead after layer 3)

    const int thr = 256;
    int gN  = (NN + thr - 1) / thr;
    int gE  = (NE + thr - 1) / thr;
    int gTile = (NN + 63) / 64;

    // ---- CSR build (bucketed two-phase) ----
    zero_all_kernel<<<gN, thr, 0, stream>>>(deg_i, bcur, NN, NBUCK);
    deg_count_kernel<<<gE, thr, 0, stream>>>(dstI, deg_i, NE);
    scan1_kernel<<<NBLK, SCAN_BLOCK, 0, stream>>>(deg_i, rowptr, bsums, NN);
    scan2_kernel<<<1, 64, 0, stream>>>(bsums, NBLK);
    scan3_kernel<<<gN, thr, 0, stream>>>(rowptr, bsums, NN);
    dinv_kernel<<<gN, thr, 0, stream>>>(deg_i, dinv, NN);
    bucketA_kernel<<<gE, thr, 0, stream>>>(srcI, dstI, rowptr, bcur, temp, NE);
    bucketB_kernel<<<NBUCK, thr, 0, stream>>>(temp, rowptr, csr_src, NN);

    // ---- conv layers: blocked transform -> 4-pass L2-resident gather ----
    dim3 gg(NN / 8, 4);
    gemm128_32_tiled<<<gTile, thr, 0, stream>>>(x, W1, t4, NN);
    gather4_kernel<<<gg, thr, 0, stream>>>(rowptr, csr_src, dinv, t4, b1, x1, NN);

    gemm32_32_kernel<<<gN, thr, 0, stream>>>(x1, W2, t4, NN);
    gather4_kernel<<<gg, thr, 0, stream>>>(rowptr, csr_src, dinv, t4, b2, x2, NN);

    gemm32_32_kernel<<<gN, thr, 0, stream>>>(x2, W3w, t4, NN);
    gather4_kernel<<<gg, thr, 0, stream>>>(rowptr, csr_src, dinv, t4, b3w, x3, NN);

    // ---- MLP head ----
    zero_pool_kernel<<<(NG * 128 + thr - 1) / thr, thr, 0, stream>>>(pooled, NG * 128);
    fc1_tiled_kernel<<<gTile, thr, 0, stream>>>(x1, x2, x3, fc1w, fc1b, h64, NN);
    fc2a_pool_kernel<<<gTile, thr, 0, stream>>>(h64, fc2aw, fc2ab, batch, pooled, NN);

    // ---- classifier ----
    head_kernel<<<(NG + thr - 1) / thr, thr, 0, stream>>>(pooled, fc2bw, fc2bb, fc3w, fc3b, out);
    (void)ws_size; (void)in_sizes; (void)n_in; (void)out_size;
}

// Round 6
// 768.923 us; speedup vs baseline: 1.5518x; 1.5518x over previous
//
#include <hip/hip_runtime.h>
#include <math.h>

#define NN 100000
#define NE 3200000
#define NG 512
#define SCAN_BLOCK 256
#define SCAN_ELEMS 1024
#define NBLK ((NN + SCAN_ELEMS - 1) / SCAN_ELEMS)
#define PSHIFT 8
#define NPART ((NN + 255) >> 8)   // 391 partitions of 256 dst nodes
#define CHUNK 4096                // edges per part1 block

typedef unsigned int uint;

__device__ inline uint bf16rne(float f) {
    uint u = __float_as_uint(f);
    return (u + 0x7fffu + ((u >> 16) & 1u)) >> 16;
}
__device__ inline float bf16lo(uint v) { return __uint_as_float(v << 16); }
__device__ inline float bf16hi(uint v) { return __uint_as_float(v & 0xffff0000u); }

// ---------------- zero degree ----------------
__global__ void zero_deg_kernel(int* deg, int n) {
    int i = blockIdx.x * blockDim.x + threadIdx.x;
    if (i < n) deg[i] = 0;
}

__global__ void zero_pool_kernel(float* p, int n) {
    int i = blockIdx.x * blockDim.x + threadIdx.x;
    if (i < n) p[i] = 0.f;
}

// ---------------- degree histogram over dst ----------------
__global__ void deg_count_kernel(const int* __restrict__ dst, int* deg, int e) {
    int i = blockIdx.x * blockDim.x + threadIdx.x;
    if (i < e) atomicAdd(&deg[dst[i]], 1);
}

// ---------------- dinv = rsqrt(deg_edges + 1) ----------------
__global__ void dinv_kernel(const int* __restrict__ deg, float* dinv, int n) {
    int i = blockIdx.x * blockDim.x + threadIdx.x;
    if (i < n) dinv[i] = rsqrtf((float)(deg[i] + 1));
}

// ---------------- scan passes ----------------
__global__ void scan1_kernel(const int* __restrict__ deg, int* __restrict__ rowptr,
                             int* __restrict__ bsums, int n) {
    __shared__ int lds[SCAN_BLOCK];
    int base = blockIdx.x * SCAN_ELEMS;
    int t = threadIdx.x;
    int v[4];
    int s = 0;
#pragma unroll
    for (int j = 0; j < 4; j++) {
        int i = base + t * 4 + j;
        v[j] = (i < n) ? deg[i] : 0;
        s += v[j];
    }
    lds[t] = s;
    __syncthreads();
    for (int off = 1; off < SCAN_BLOCK; off <<= 1) {
        int val = (t >= off) ? lds[t - off] : 0;
        __syncthreads();
        lds[t] += val;
        __syncthreads();
    }
    int run = (t > 0) ? lds[t - 1] : 0;
    if (t == SCAN_BLOCK - 1) bsums[blockIdx.x] = lds[t];
#pragma unroll
    for (int j = 0; j < 4; j++) {
        int i = base + t * 4 + j;
        run += v[j];
        if (i < n) rowptr[i + 1] = run;
    }
}

__global__ void scan2_kernel(int* bsums, int nb) {
    if (threadIdx.x == 0 && blockIdx.x == 0) {
        int acc = 0;
        for (int b = 0; b < nb; b++) { int v = bsums[b]; bsums[b] = acc; acc += v; }
    }
}

__global__ void scan3_kernel(int* rowptr, const int* __restrict__ bsums, int n) {
    int i = blockIdx.x * blockDim.x + threadIdx.x;
    if (i == 0) rowptr[0] = 0;
    if (i < n) rowptr[i + 1] += bsums[i / SCAN_ELEMS];
}

// ---------------- init partition cursors + per-node cursors ----------------
__global__ void pinit_kernel(const int* __restrict__ rowptr, int* pcur, int* cursor, int n) {
    int i = blockIdx.x * blockDim.x + threadIdx.x;
    if (i < n) cursor[i] = 0;
    if (i < NPART) pcur[i] = rowptr[i << PSHIFT];
}

// ---------------- part1: LDS-binned partition scatter ----------------
// Bins CHUNK edges into NPART dst-range partitions in LDS, reserves a
// contiguous global range per (block,partition), flushes packed (src<<8)|dlo.
__global__ __launch_bounds__(256) void part1_kernel(
    const int* __restrict__ src, const int* __restrict__ dst,
    int* pcur, int* __restrict__ temp, int e) {
    __shared__ int cnt[NPART + 1];
    __shared__ int gbase[NPART + 1];
    int t = threadIdx.x;
    for (int i = t; i < NPART; i += 256) cnt[i] = 0;
    __syncthreads();
    int base = blockIdx.x * CHUNK;
    int pv[16], pp[16], rr[16];
#pragma unroll
    for (int j = 0; j < 16; j++) {
        int i = base + j * 256 + t;
        if (i < e) {
            int s = src[i], d = dst[i];
            pp[j] = d >> PSHIFT;
            pv[j] = (s << PSHIFT) | (d & 255);
            rr[j] = atomicAdd(&cnt[pp[j]], 1);
        } else {
            pp[j] = -1; pv[j] = 0; rr[j] = 0;
        }
    }
    __syncthreads();
    for (int i = t; i < NPART; i += 256)
        gbase[i] = cnt[i] ? atomicAdd(&pcur[i], cnt[i]) : 0;
    __syncthreads();
#pragma unroll
    for (int j = 0; j < 16; j++)
        if (pp[j] >= 0) temp[gbase[pp[j]] + rr[j]] = pv[j];
}

// ---------------- part2: within-partition scatter to exact CSR slots ----------------
// Partition csr window ~33 KB -> L2-resident, no write amplification.
__global__ __launch_bounds__(256) void part2_kernel(
    const int* __restrict__ temp, const int* __restrict__ rowptr, int* cursor,
    int* __restrict__ csr_src, int n) {
    int p = blockIdx.x, sp = blockIdx.y;
    int d0 = p << PSHIFT;
    int lo = rowptr[d0];
    int hi = rowptr[min(d0 + 256, n)];
    for (int i = lo + sp * 256 + threadIdx.x; i < hi; i += 1024) {
        int v = temp[i];
        int d = d0 + (v & 255);
        int slot = rowptr[d] + atomicAdd(&cursor[d], 1);
        csr_src[slot] = v >> PSHIFT;
    }
}

// ---------------- tb[n,32] (bf16) = x[n,128] @ W[128,32] ----------------
__global__ __launch_bounds__(256) void gemm128_32_tiled(
    const float* __restrict__ x, const float* __restrict__ W, uint* __restrict__ tb, int n) {
    __shared__ float Wl[128 * 32];   // 16 KB
    __shared__ float Xl[64 * 132];   // 33.8 KB
    int t = threadIdx.x;
    for (int i = t; i < 128 * 32; i += 256) Wl[i] = W[i];
    int tile0 = blockIdx.x * 64;
    for (int idx = t; idx < 64 * 128; idx += 256) {
        int r = idx >> 7, k = idx & 127;
        int node = tile0 + r;
        Xl[r * 132 + k] = (node < n) ? x[(long long)node * 128 + k] : 0.f;
    }
    __syncthreads();
    int cg = t & 7, ng = t >> 3;
    int c0 = cg * 4;
    float acc[2][4];
#pragma unroll
    for (int i = 0; i < 2; i++)
        for (int j = 0; j < 4; j++) acc[i][j] = 0.f;
    for (int k = 0; k < 128; k++) {
        float4 w = *(const float4*)&Wl[k * 32 + c0];
#pragma unroll
        for (int i = 0; i < 2; i++) {
            float a = Xl[(ng * 2 + i) * 132 + k];
            acc[i][0] += a * w.x; acc[i][1] += a * w.y;
            acc[i][2] += a * w.z; acc[i][3] += a * w.w;
        }
    }
#pragma unroll
    for (int i = 0; i < 2; i++) {
        int node = tile0 + ng * 2 + i;
        if (node < n) {
            uint2 pk;
            pk.x = bf16rne(acc[i][0]) | (bf16rne(acc[i][1]) << 16);
            pk.y = bf16rne(acc[i][2]) | (bf16rne(acc[i][3]) << 16);
            *(uint2*)&tb[node * 16 + (c0 >> 1)] = pk;
        }
    }
}

// ---------------- tb[n,32] (bf16) = xin[n,32] @ W[32,32] ----------------
__global__ void gemm32_32_kernel(const float* __restrict__ xin, const float* __restrict__ W,
                                 uint* __restrict__ tb, int n) {
    __shared__ float Wl[32 * 32];
    for (int i = threadIdx.x; i < 32 * 32; i += blockDim.x) Wl[i] = W[i];
    __syncthreads();
    int node = blockIdx.x * blockDim.x + threadIdx.x;
    if (node >= n) return;
    float acc[32];
#pragma unroll
    for (int k = 0; k < 32; k++) acc[k] = 0.f;
    const float4* xp = (const float4*)(xin + (long long)node * 32);
#pragma unroll
    for (int j4 = 0; j4 < 8; j4++) {
        float4 v4 = xp[j4];
        float vv[4] = {v4.x, v4.y, v4.z, v4.w};
#pragma unroll
        for (int c = 0; c < 4; c++) {
            const float* wr = &Wl[(j4 * 4 + c) * 32];
#pragma unroll
            for (int k = 0; k < 32; k++) acc[k] += vv[c] * wr[k];
        }
    }
#pragma unroll
    for (int q = 0; q < 4; q++) {
        uint4 pk;
        pk.x = bf16rne(acc[q * 8 + 0]) | (bf16rne(acc[q * 8 + 1]) << 16);
        pk.y = bf16rne(acc[q * 8 + 2]) | (bf16rne(acc[q * 8 + 3]) << 16);
        pk.z = bf16rne(acc[q * 8 + 4]) | (bf16rne(acc[q * 8 + 5]) << 16);
        pk.w = bf16rne(acc[q * 8 + 6]) | (bf16rne(acc[q * 8 + 7]) << 16);
        *(uint4*)&tb[node * 16 + q * 4] = pk;
    }
}

// ---------------- pull aggregation (bf16 t) + bias + relu ----------------
// 32 lanes/node: 2 edge-slots x 16 feature-pairs. t-row = 64 B.
__global__ __launch_bounds__(256) void gather_bf16_kernel(
    const int* __restrict__ rowptr, const int* __restrict__ csr_src,
    const float* __restrict__ dinv, const uint* __restrict__ tb,
    const float* __restrict__ bias, float* __restrict__ xo, int n) {
    int tid = blockIdx.x * blockDim.x + threadIdx.x;
    int node = tid >> 5;
    if (node >= n) return;
    int lane = tid & 31;
    int sub = lane >> 4, fp = lane & 15;
    float dd = dinv[node];
    int beg = rowptr[node], end = rowptr[node + 1];
    float a0 = 0.f, a1 = 0.f;
    for (int e = beg + sub; e < end; e += 2) {
        int s = csr_src[e];
        float w = dinv[s];
        uint v = tb[s * 16 + fp];
        a0 += bf16lo(v) * w;
        a1 += bf16hi(v) * w;
    }
    a0 += __shfl_xor(a0, 16, 64);
    a1 += __shfl_xor(a1, 16, 64);
    if (sub == 0) {
        uint sv = tb[node * 16 + fp];
        a0 += bf16lo(sv) * dd;
        a1 += bf16hi(sv) * dd;
        float2 bb = ((const float2*)bias)[fp];
        float2 r;
        r.x = fmaxf(a0 * dd + bb.x, 0.f);
        r.y = fmaxf(a1 * dd + bb.y, 0.f);
        ((float2*)xo)[node * 16 + fp] = r;
    }
}

// ---------------- h64 = relu(concat(x1,x2,x3) @ fc1_w + fc1_b) ----------------
__global__ __launch_bounds__(256) void fc1_tiled_kernel(
    const float* __restrict__ x1, const float* __restrict__ x2, const float* __restrict__ x3,
    const float* __restrict__ W, const float* __restrict__ b, float* __restrict__ h64, int n) {
    __shared__ float Wl[96 * 64];   // 24 KB
    __shared__ float Xl[64][97];    // 24.8 KB
    int t = threadIdx.x;
    for (int i = t; i < 96 * 64; i += 256) Wl[i] = W[i];
    int tile0 = blockIdx.x * 64;
    for (int idx = t; idx < 64 * 32; idx += 256) {
        int r = idx >> 5, j = idx & 31;
        int node = tile0 + r;
        float v1 = 0.f, v2 = 0.f, v3 = 0.f;
        if (node < n) {
            v1 = x1[node * 32 + j];
            v2 = x2[node * 32 + j];
            v3 = x3[node * 32 + j];
        }
        Xl[r][j] = v1; Xl[r][32 + j] = v2; Xl[r][64 + j] = v3;
    }
    __syncthreads();
    int cg = t & 15, ng = t >> 4;
    int c0 = cg * 4;
    float4 bb = *(const float4*)&b[c0];
    float acc[4][4];
#pragma unroll
    for (int i = 0; i < 4; i++) {
        acc[i][0] = bb.x; acc[i][1] = bb.y; acc[i][2] = bb.z; acc[i][3] = bb.w;
    }
    for (int k = 0; k < 96; k++) {
        float4 w = *(const float4*)&Wl[k * 64 + c0];
#pragma unroll
        for (int i = 0; i < 4; i++) {
            float a = Xl[ng * 4 + i][k];
            acc[i][0] += a * w.x; acc[i][1] += a * w.y;
            acc[i][2] += a * w.z; acc[i][3] += a * w.w;
        }
    }
#pragma unroll
    for (int i = 0; i < 4; i++) {
        int node = tile0 + ng * 4 + i;
        if (node < n)
            *(float4*)&h64[node * 64 + c0] =
                make_float4(fmaxf(acc[i][0], 0.f), fmaxf(acc[i][1], 0.f),
                            fmaxf(acc[i][2], 0.f), fmaxf(acc[i][3], 0.f));
    }
}

// ---------------- h128 = relu(h64 @ fc2a_w + b) fused with segment pooling ----------------
__global__ __launch_bounds__(256) void fc2a_pool_kernel(
    const float* __restrict__ h64, const float* __restrict__ W, const float* __restrict__ b,
    const int* __restrict__ batch, float* __restrict__ pooled, int n) {
    __shared__ float Wl[64 * 128];  // 32 KB
    __shared__ float Al[64 * 64];   // 16 KB
    __shared__ int batchl[64];
    int t = threadIdx.x;
    for (int i = t; i < 64 * 128; i += 256) Wl[i] = W[i];
    int tile0 = blockIdx.x * 64;
    for (int idx = t; idx < 64 * 64; idx += 256) {
        int r = idx >> 6, k = idx & 63;
        int node = tile0 + r;
        Al[idx] = (node < n) ? h64[node * 64 + k] : 0.f;
    }
    if (t < 64) batchl[t] = (tile0 + t < n) ? batch[tile0 + t] : -1;
    __syncthreads();
    int cg = t & 31, ng = t >> 5;
    int c0 = cg * 4;
    float acc[8][4];
#pragma unroll
    for (int i = 0; i < 8; i++)
        for (int j = 0; j < 4; j++) acc[i][j] = 0.f;
    for (int k = 0; k < 64; k++) {
        float4 w = *(const float4*)&Wl[k * 128 + c0];
#pragma unroll
        for (int i = 0; i < 8; i++) {
            float a = Al[(ng * 8 + i) * 64 + k];
            acc[i][0] += a * w.x; acc[i][1] += a * w.y;
            acc[i][2] += a * w.z; acc[i][3] += a * w.w;
        }
    }
    float4 bb = *(const float4*)&b[c0];
    int base = ng * 8;
    if (tile0 + base < n) {
        float r0 = 0.f, r1 = 0.f, r2 = 0.f, r3 = 0.f;
        int curg = batchl[base];
        for (int i = 0; i < 8; i++) {
            int node = tile0 + base + i;
            if (node >= n) break;
            int gi = batchl[base + i];
            if (gi != curg) {
                float* dst = pooled + (long long)curg * 128 + c0;
                atomicAdd(dst + 0, r0); atomicAdd(dst + 1, r1);
                atomicAdd(dst + 2, r2); atomicAdd(dst + 3, r3);
                r0 = r1 = r2 = r3 = 0.f;
                curg = gi;
            }
            r0 += fmaxf(acc[i][0] + bb.x, 0.f);
            r1 += fmaxf(acc[i][1] + bb.y, 0.f);
            r2 += fmaxf(acc[i][2] + bb.z, 0.f);
            r3 += fmaxf(acc[i][3] + bb.w, 0.f);
        }
        float* dst = pooled + (long long)curg * 128 + c0;
        atomicAdd(dst + 0, r0); atomicAdd(dst + 1, r1);
        atomicAdd(dst + 2, r2); atomicAdd(dst + 3, r3);
    }
}

// ---------------- classifier ----------------
__global__ void head_kernel(const float* __restrict__ pooled, const float* __restrict__ W2b,
                            const float* __restrict__ b2b, const float* __restrict__ W3,
                            const float* __restrict__ b3, float* __restrict__ out) {
    __shared__ float Wl[128 * 64];
    for (int i = threadIdx.x; i < 128 * 64; i += blockDim.x) Wl[i] = W2b[i];
    __syncthreads();
    int g = blockIdx.x * blockDim.x + threadIdx.x;
    if (g >= NG) return;
    float acc[64];
#pragma unroll
    for (int k = 0; k < 64; k++) acc[k] = b2b[k];
    const float* p0 = pooled + (long long)g * 128;
    for (int j = 0; j < 128; j++) {
        float v = p0[j];
        const float* wr = &Wl[j * 64];
#pragma unroll
        for (int k = 0; k < 64; k++) acc[k] += v * wr[k];
    }
    float l0 = b3[0], l1 = b3[1];
#pragma unroll
    for (int k = 0; k < 64; k++) {
        float h = fmaxf(acc[k], 0.f);
        l0 += h * W3[k * 2 + 0];
        l1 += h * W3[k * 2 + 1];
    }
    float m = fmaxf(l0, l1);
    float lse = m + logf(expf(l0 - m) + expf(l1 - m));
    out[g * 2 + 0] = l0 - lse;
    out[g * 2 + 1] = l1 - lse;
}

extern "C" void kernel_launch(void* const* d_in, const int* in_sizes, int n_in,
                              void* d_out, int out_size, void* d_ws, size_t ws_size,
                              hipStream_t stream) {
    const float* x     = (const float*)d_in[0];
    const int*   ei    = (const int*)d_in[1];
    const int*   srcI  = ei;
    const int*   dstI  = ei + NE;
    const int*   batch = (const int*)d_in[2];
    const float* W1    = (const float*)d_in[3];
    const float* b1    = (const float*)d_in[4];
    const float* W2    = (const float*)d_in[5];
    const float* b2    = (const float*)d_in[6];
    const float* W3w   = (const float*)d_in[7];
    const float* b3w   = (const float*)d_in[8];
    const float* fc1w  = (const float*)d_in[9];
    const float* fc1b  = (const float*)d_in[10];
    const float* fc2aw = (const float*)d_in[11];
    const float* fc2ab = (const float*)d_in[12];
    const float* fc2bw = (const float*)d_in[13];
    const float* fc2bb = (const float*)d_in[14];
    const float* fc3w  = (const float*)d_in[15];
    const float* fc3b  = (const float*)d_in[16];
    float* out = (float*)d_out;

    // ---- workspace layout ----
    char* p = (char*)d_ws;
    int* deg_i = (int*)p;                 p += (size_t)NN * 4;     // doubles as cursor
    int* rowptr = (int*)p;                p += (size_t)(NN + 4) * 4;
    int* bsums = (int*)p;                 p += 4096;
    int* pcur = (int*)p;                  p += 2048;
    float* dinv = (float*)p;              p += (size_t)NN * 4;
    int* temp = (int*)p;                  p += (size_t)NE * 4;     // 12.8 MB
    int* csr_src = (int*)p;               p += (size_t)NE * 4;     // 12.8 MB
    uint* tb = (uint*)p;                  p += (size_t)NN * 16 * 4; // 6.4 MB bf16 t
    float* x1 = (float*)p;                p += (size_t)NN * 32 * 4;
    float* x2 = (float*)p;                p += (size_t)NN * 32 * 4;
    float* x3 = (float*)p;                p += (size_t)NN * 32 * 4;
    float* pooled = (float*)p;            p += (size_t)NG * 128 * 4;
    float* h64 = (float*)temp;            // alias temp+csr_src (25.6 MB, dead after layer 3)
    int* cursor = deg_i;                  // deg dead after dinv

    const int thr = 256;
    int gN  = (NN + thr - 1) / thr;
    int gE  = (NE + thr - 1) / thr;
    int gTile = (NN + 63) / 64;
    int gGather = (NN * 32 + thr - 1) / thr;

    // ---- CSR build: histogram -> scan -> LDS-binned partition -> local scatter ----
    zero_deg_kernel<<<gN, thr, 0, stream>>>(deg_i, NN);
    deg_count_kernel<<<gE, thr, 0, stream>>>(dstI, deg_i, NE);
    scan1_kernel<<<NBLK, SCAN_BLOCK, 0, stream>>>(deg_i, rowptr, bsums, NN);
    scan2_kernel<<<1, 64, 0, stream>>>(bsums, NBLK);
    scan3_kernel<<<gN, thr, 0, stream>>>(rowptr, bsums, NN);
    dinv_kernel<<<gN, thr, 0, stream>>>(deg_i, dinv, NN);
    pinit_kernel<<<gN, thr, 0, stream>>>(rowptr, pcur, cursor, NN);
    part1_kernel<<<(NE + CHUNK - 1) / CHUNK, thr, 0, stream>>>(srcI, dstI, pcur, temp, NE);
    dim3 p2g(NPART, 4);
    part2_kernel<<<p2g, thr, 0, stream>>>(temp, rowptr, cursor, csr_src, NN);

    // ---- conv layers: transform (bf16 out) -> pull gather ----
    gemm128_32_tiled<<<gTile, thr, 0, stream>>>(x, W1, tb, NN);
    gather_bf16_kernel<<<gGather, thr, 0, stream>>>(rowptr, csr_src, dinv, tb, b1, x1, NN);

    gemm32_32_kernel<<<gN, thr, 0, stream>>>(x1, W2, tb, NN);
    gather_bf16_kernel<<<gGather, thr, 0, stream>>>(rowptr, csr_src, dinv, tb, b2, x2, NN);

    gemm32_32_kernel<<<gN, thr, 0, stream>>>(x2, W3w, tb, NN);
    gather_bf16_kernel<<<gGather, thr, 0, stream>>>(rowptr, csr_src, dinv, tb, b3w, x3, NN);

    // ---- MLP head ----
    zero_pool_kernel<<<(NG * 128 + thr - 1) / thr, thr, 0, stream>>>(pooled, NG * 128);
    fc1_tiled_kernel<<<gTile, thr, 0, stream>>>(x1, x2, x3, fc1w, fc1b, h64, NN);
    fc2a_pool_kernel<<<gTile, thr, 0, stream>>>(h64, fc2aw, fc2ab, batch, pooled, NN);

    // ---- classifier ----
    head_kernel<<<(NG + thr - 1) / thr, thr, 0, stream>>>(pooled, fc2bw, fc2bb, fc3w, fc3b, out);
    (void)ws_size; (void)in_sizes; (void)n_in; (void)out_size;
}

// Round 7
// 596.791 us; speedup vs baseline: 1.9994x; 1.2884x over previous
//
#include <hip/hip_runtime.h>
#include <math.h>

#define NN 100000
#define NE 3200000
#define NG 512
#define PSHIFT 8
#define NPART ((NN + 255) >> 8)   // 391 partitions of 256 dst nodes
#define CHUNK 4096                // edges per binning block

typedef unsigned int uint;

__device__ inline uint bf16rne(float f) {
    uint u = __float_as_uint(f);
    return (u + 0x7fffu + ((u >> 16) & 1u)) >> 16;
}
__device__ inline float bf16lo(uint v) { return __uint_as_float(v << 16); }
__device__ inline float bf16hi(uint v) { return __uint_as_float(v & 0xffff0000u); }

// ---------------- zero pcnt + pooled ----------------
__global__ void zero_misc_kernel(int* pcnt, float* pooled) {
    int i = blockIdx.x * blockDim.x + threadIdx.x;
    if (i < NPART) pcnt[i] = 0;
    if (i < NG * 128) pooled[i] = 0.f;
}

// ---------------- partition-level histogram (LDS-binned) ----------------
__global__ __launch_bounds__(256) void phist_kernel(const int* __restrict__ dst,
                                                    int* pcnt, int e) {
    __shared__ int cnt[NPART];
    int t = threadIdx.x;
    for (int i = t; i < NPART; i += 256) cnt[i] = 0;
    __syncthreads();
    int base = blockIdx.x * CHUNK;
#pragma unroll
    for (int j = 0; j < 16; j++) {
        int i = base + j * 256 + t;
        if (i < e) atomicAdd(&cnt[dst[i] >> PSHIFT], 1);
    }
    __syncthreads();
    for (int i = t; i < NPART; i += 256)
        if (cnt[i]) atomicAdd(&pcnt[i], cnt[i]);
}

// ---------------- one-block LDS scan of partition counts ----------------
__global__ __launch_bounds__(512) void scanP_kernel(const int* __restrict__ pcnt,
                                                    int* pbase, int* pcur) {
    __shared__ int s[512];
    int t = threadIdx.x;
    s[t] = (t < NPART) ? pcnt[t] : 0;
    __syncthreads();
    for (int off = 1; off < 512; off <<= 1) {
        int v = (t >= off) ? s[t - off] : 0;
        __syncthreads();
        s[t] += v;
        __syncthreads();
    }
    int ex = (t > 0) ? s[t - 1] : 0;
    if (t <= NPART) pbase[t] = ex;
    if (t < NPART) pcur[t] = ex;
}

// ---------------- part1: LDS-binned partition scatter ----------------
__global__ __launch_bounds__(256) void part1_kernel(
    const int* __restrict__ src, const int* __restrict__ dst,
    int* pcur, int* __restrict__ temp, int e) {
    __shared__ int cnt[NPART];
    __shared__ int gbase[NPART];
    int t = threadIdx.x;
    for (int i = t; i < NPART; i += 256) cnt[i] = 0;
    __syncthreads();
    int base = blockIdx.x * CHUNK;
    int pv[16], pp[16], rr[16];
#pragma unroll
    for (int j = 0; j < 16; j++) {
        int i = base + j * 256 + t;
        if (i < e) {
            int s = src[i], d = dst[i];
            pp[j] = d >> PSHIFT;
            pv[j] = (s << PSHIFT) | (d & 255);
            rr[j] = atomicAdd(&cnt[pp[j]], 1);
        } else {
            pp[j] = -1; pv[j] = 0; rr[j] = 0;
        }
    }
    __syncthreads();
    for (int i = t; i < NPART; i += 256)
        gbase[i] = cnt[i] ? atomicAdd(&pcur[i], cnt[i]) : 0;
    __syncthreads();
#pragma unroll
    for (int j = 0; j < 16; j++)
        if (pp[j] >= 0) temp[gbase[pp[j]] + rr[j]] = pv[j];
}

// ---------------- part2: per-partition degree count + local scan + scatter ----------------
// All per-edge atomics in LDS; rowptr/dinv derived here (no global scan needed).
__global__ __launch_bounds__(256) void part2_kernel(
    const int* __restrict__ temp, const int* __restrict__ pbase,
    int* __restrict__ rowptr, float* __restrict__ dinv,
    int* __restrict__ csr_src, int n) {
    __shared__ int cnt[256];
    __shared__ int sc[256];
    int p = blockIdx.x;
    int d0 = p << PSHIFT;
    int t = threadIdx.x;
    cnt[t] = 0;
    __syncthreads();
    int lo = pbase[p], hi = pbase[p + 1];
    for (int i = lo + t; i < hi; i += 256) atomicAdd(&cnt[temp[i] & 255], 1);
    __syncthreads();
    int myc = cnt[t];
    sc[t] = myc;
    __syncthreads();
    for (int off = 1; off < 256; off <<= 1) {
        int v = (t >= off) ? sc[t - off] : 0;
        __syncthreads();
        sc[t] += v;
        __syncthreads();
    }
    int ex = (t > 0) ? sc[t - 1] : 0;   // exclusive scan
    int d = d0 + t;
    if (d < n) {
        rowptr[d] = lo + ex;
        dinv[d] = rsqrtf((float)(myc + 1));
    }
    if (d == n) rowptr[n] = lo + ex;
    __syncthreads();
    cnt[t] = 0;                          // reuse as cursor
    sc[t] = lo + ex;                     // local rowptr base, stable in LDS
    __syncthreads();
    for (int i = lo + t; i < hi; i += 256) {
        int v = temp[i];
        int ld = v & 255;
        int slot = sc[ld] + atomicAdd(&cnt[ld], 1);
        csr_src[slot] = v >> PSHIFT;
    }
}

// ---------------- tb[n,32] (bf16) = x[n,128] @ W[128,32] ----------------
__global__ __launch_bounds__(256) void gemm128_32_tiled(
    const float* __restrict__ x, const float* __restrict__ W, uint* __restrict__ tb, int n) {
    __shared__ float Wl[128 * 32];   // 16 KB
    __shared__ float Xl[64 * 132];   // 33.8 KB
    int t = threadIdx.x;
    for (int i = t; i < 128 * 32; i += 256) Wl[i] = W[i];
    int tile0 = blockIdx.x * 64;
    for (int idx = t; idx < 64 * 128; idx += 256) {
        int r = idx >> 7, k = idx & 127;
        int node = tile0 + r;
        Xl[r * 132 + k] = (node < n) ? x[(long long)node * 128 + k] : 0.f;
    }
    __syncthreads();
    int cg = t & 7, ng = t >> 3;
    int c0 = cg * 4;
    float acc[2][4];
#pragma unroll
    for (int i = 0; i < 2; i++)
        for (int j = 0; j < 4; j++) acc[i][j] = 0.f;
    for (int k = 0; k < 128; k++) {
        float4 w = *(const float4*)&Wl[k * 32 + c0];
#pragma unroll
        for (int i = 0; i < 2; i++) {
            float a = Xl[(ng * 2 + i) * 132 + k];
            acc[i][0] += a * w.x; acc[i][1] += a * w.y;
            acc[i][2] += a * w.z; acc[i][3] += a * w.w;
        }
    }
#pragma unroll
    for (int i = 0; i < 2; i++) {
        int node = tile0 + ng * 2 + i;
        if (node < n) {
            uint2 pk;
            pk.x = bf16rne(acc[i][0]) | (bf16rne(acc[i][1]) << 16);
            pk.y = bf16rne(acc[i][2]) | (bf16rne(acc[i][3]) << 16);
            *(uint2*)&tb[node * 16 + (c0 >> 1)] = pk;
        }
    }
}

// ---------------- tb[n,32] (bf16) = xin[n,32] @ W[32,32] ----------------
__global__ void gemm32_32_kernel(const float* __restrict__ xin, const float* __restrict__ W,
                                 uint* __restrict__ tb, int n) {
    __shared__ float Wl[32 * 32];
    for (int i = threadIdx.x; i < 32 * 32; i += blockDim.x) Wl[i] = W[i];
    __syncthreads();
    int node = blockIdx.x * blockDim.x + threadIdx.x;
    if (node >= n) return;
    float acc[32];
#pragma unroll
    for (int k = 0; k < 32; k++) acc[k] = 0.f;
    const float4* xp = (const float4*)(xin + (long long)node * 32);
#pragma unroll
    for (int j4 = 0; j4 < 8; j4++) {
        float4 v4 = xp[j4];
        float vv[4] = {v4.x, v4.y, v4.z, v4.w};
#pragma unroll
        for (int c = 0; c < 4; c++) {
            const float* wr = &Wl[(j4 * 4 + c) * 32];
#pragma unroll
            for (int k = 0; k < 32; k++) acc[k] += vv[c] * wr[k];
        }
    }
#pragma unroll
    for (int q = 0; q < 4; q++) {
        uint4 pk;
        pk.x = bf16rne(acc[q * 8 + 0]) | (bf16rne(acc[q * 8 + 1]) << 16);
        pk.y = bf16rne(acc[q * 8 + 2]) | (bf16rne(acc[q * 8 + 3]) << 16);
        pk.z = bf16rne(acc[q * 8 + 4]) | (bf16rne(acc[q * 8 + 5]) << 16);
        pk.w = bf16rne(acc[q * 8 + 6]) | (bf16rne(acc[q * 8 + 7]) << 16);
        *(uint4*)&tb[node * 16 + q * 4] = pk;
    }
}

// ---------------- pull aggregation (bf16 t) + bias + relu ----------------
__global__ __launch_bounds__(256) void gather_bf16_kernel(
    const int* __restrict__ rowptr, const int* __restrict__ csr_src,
    const float* __restrict__ dinv, const uint* __restrict__ tb,
    const float* __restrict__ bias, float* __restrict__ xo, int n) {
    int tid = blockIdx.x * blockDim.x + threadIdx.x;
    int node = tid >> 5;
    if (node >= n) return;
    int lane = tid & 31;
    int sub = lane >> 4, fp = lane & 15;
    float dd = dinv[node];
    int beg = rowptr[node], end = rowptr[node + 1];
    float a0 = 0.f, a1 = 0.f;
    for (int e = beg + sub; e < end; e += 2) {
        int s = csr_src[e];
        float w = dinv[s];
        uint v = tb[s * 16 + fp];
        a0 += bf16lo(v) * w;
        a1 += bf16hi(v) * w;
    }
    a0 += __shfl_xor(a0, 16, 64);
    a1 += __shfl_xor(a1, 16, 64);
    if (sub == 0) {
        uint sv = tb[node * 16 + fp];
        a0 += bf16lo(sv) * dd;
        a1 += bf16hi(sv) * dd;
        float2 bb = ((const float2*)bias)[fp];
        float2 r;
        r.x = fmaxf(a0 * dd + bb.x, 0.f);
        r.y = fmaxf(a1 * dd + bb.y, 0.f);
        ((float2*)xo)[node * 16 + fp] = r;
    }
}

// ---------------- h64 = relu(concat(x1,x2,x3) @ fc1_w + fc1_b) ----------------
__global__ __launch_bounds__(256) void fc1_tiled_kernel(
    const float* __restrict__ x1, const float* __restrict__ x2, const float* __restrict__ x3,
    const float* __restrict__ W, const float* __restrict__ b, float* __restrict__ h64, int n) {
    __shared__ float Wl[96 * 64];   // 24 KB
    __shared__ float Xl[64][97];    // 24.8 KB
    int t = threadIdx.x;
    for (int i = t; i < 96 * 64; i += 256) Wl[i] = W[i];
    int tile0 = blockIdx.x * 64;
    for (int idx = t; idx < 64 * 32; idx += 256) {
        int r = idx >> 5, j = idx & 31;
        int node = tile0 + r;
        float v1 = 0.f, v2 = 0.f, v3 = 0.f;
        if (node < n) {
            v1 = x1[node * 32 + j];
            v2 = x2[node * 32 + j];
            v3 = x3[node * 32 + j];
        }
        Xl[r][j] = v1; Xl[r][32 + j] = v2; Xl[r][64 + j] = v3;
    }
    __syncthreads();
    int cg = t & 15, ng = t >> 4;
    int c0 = cg * 4;
    float4 bb = *(const float4*)&b[c0];
    float acc[4][4];
#pragma unroll
    for (int i = 0; i < 4; i++) {
        acc[i][0] = bb.x; acc[i][1] = bb.y; acc[i][2] = bb.z; acc[i][3] = bb.w;
    }
    for (int k = 0; k < 96; k++) {
        float4 w = *(const float4*)&Wl[k * 64 + c0];
#pragma unroll
        for (int i = 0; i < 4; i++) {
            float a = Xl[ng * 4 + i][k];
            acc[i][0] += a * w.x; acc[i][1] += a * w.y;
            acc[i][2] += a * w.z; acc[i][3] += a * w.w;
        }
    }
#pragma unroll
    for (int i = 0; i < 4; i++) {
        int node = tile0 + ng * 4 + i;
        if (node < n)
            *(float4*)&h64[node * 64 + c0] =
                make_float4(fmaxf(acc[i][0], 0.f), fmaxf(acc[i][1], 0.f),
                            fmaxf(acc[i][2], 0.f), fmaxf(acc[i][3], 0.f));
    }
}

// ---------------- h128 = relu(h64 @ fc2a_w + b) fused with segment pooling ----------------
__global__ __launch_bounds__(256) void fc2a_pool_kernel(
    const float* __restrict__ h64, const float* __restrict__ W, const float* __restrict__ b,
    const int* __restrict__ batch, float* __restrict__ pooled, int n) {
    __shared__ float Wl[64 * 128];  // 32 KB
    __shared__ float Al[64 * 64];   // 16 KB
    __shared__ int batchl[64];
    int t = threadIdx.x;
    for (int i = t; i < 64 * 128; i += 256) Wl[i] = W[i];
    int tile0 = blockIdx.x * 64;
    for (int idx = t; idx < 64 * 64; idx += 256) {
        int r = idx >> 6, k = idx & 63;
        int node = tile0 + r;
        Al[idx] = (node < n) ? h64[node * 64 + k] : 0.f;
    }
    if (t < 64) batchl[t] = (tile0 + t < n) ? batch[tile0 + t] : -1;
    __syncthreads();
    int cg = t & 31, ng = t >> 5;
    int c0 = cg * 4;
    float acc[8][4];
#pragma unroll
    for (int i = 0; i < 8; i++)
        for (int j = 0; j < 4; j++) acc[i][j] = 0.f;
    for (int k = 0; k < 64; k++) {
        float4 w = *(const float4*)&Wl[k * 128 + c0];
#pragma unroll
        for (int i = 0; i < 8; i++) {
            float a = Al[(ng * 8 + i) * 64 + k];
            acc[i][0] += a * w.x; acc[i][1] += a * w.y;
            acc[i][2] += a * w.z; acc[i][3] += a * w.w;
        }
    }
    float4 bb = *(const float4*)&b[c0];
    int base = ng * 8;
    if (tile0 + base < n) {
        float r0 = 0.f, r1 = 0.f, r2 = 0.f, r3 = 0.f;
        int curg = batchl[base];
        for (int i = 0; i < 8; i++) {
            int node = tile0 + base + i;
            if (node >= n) break;
            int gi = batchl[base + i];
            if (gi != curg) {
                float* dst = pooled + (long long)curg * 128 + c0;
                atomicAdd(dst + 0, r0); atomicAdd(dst + 1, r1);
                atomicAdd(dst + 2, r2); atomicAdd(dst + 3, r3);
                r0 = r1 = r2 = r3 = 0.f;
                curg = gi;
            }
            r0 += fmaxf(acc[i][0] + bb.x, 0.f);
            r1 += fmaxf(acc[i][1] + bb.y, 0.f);
            r2 += fmaxf(acc[i][2] + bb.z, 0.f);
            r3 += fmaxf(acc[i][3] + bb.w, 0.f);
        }
        float* dst = pooled + (long long)curg * 128 + c0;
        atomicAdd(dst + 0, r0); atomicAdd(dst + 1, r1);
        atomicAdd(dst + 2, r2); atomicAdd(dst + 3, r3);
    }
}

// ---------------- classifier ----------------
__global__ void head_kernel(const float* __restrict__ pooled, const float* __restrict__ W2b,
                            const float* __restrict__ b2b, const float* __restrict__ W3,
                            const float* __restrict__ b3, float* __restrict__ out) {
    __shared__ float Wl[128 * 64];
    for (int i = threadIdx.x; i < 128 * 64; i += blockDim.x) Wl[i] = W2b[i];
    __syncthreads();
    int g = blockIdx.x * blockDim.x + threadIdx.x;
    if (g >= NG) return;
    float acc[64];
#pragma unroll
    for (int k = 0; k < 64; k++) acc[k] = b2b[k];
    const float* p0 = pooled + (long long)g * 128;
    for (int j = 0; j < 128; j++) {
        float v = p0[j];
        const float* wr = &Wl[j * 64];
#pragma unroll
        for (int k = 0; k < 64; k++) acc[k] += v * wr[k];
    }
    float l0 = b3[0], l1 = b3[1];
#pragma unroll
    for (int k = 0; k < 64; k++) {
        float h = fmaxf(acc[k], 0.f);
        l0 += h * W3[k * 2 + 0];
        l1 += h * W3[k * 2 + 1];
    }
    float m = fmaxf(l0, l1);
    float lse = m + logf(expf(l0 - m) + expf(l1 - m));
    out[g * 2 + 0] = l0 - lse;
    out[g * 2 + 1] = l1 - lse;
}

extern "C" void kernel_launch(void* const* d_in, const int* in_sizes, int n_in,
                              void* d_out, int out_size, void* d_ws, size_t ws_size,
                              hipStream_t stream) {
    const float* x     = (const float*)d_in[0];
    const int*   ei    = (const int*)d_in[1];
    const int*   srcI  = ei;
    const int*   dstI  = ei + NE;
    const int*   batch = (const int*)d_in[2];
    const float* W1    = (const float*)d_in[3];
    const float* b1    = (const float*)d_in[4];
    const float* W2    = (const float*)d_in[5];
    const float* b2    = (const float*)d_in[6];
    const float* W3w   = (const float*)d_in[7];
    const float* b3w   = (const float*)d_in[8];
    const float* fc1w  = (const float*)d_in[9];
    const float* fc1b  = (const float*)d_in[10];
    const float* fc2aw = (const float*)d_in[11];
    const float* fc2ab = (const float*)d_in[12];
    const float* fc2bw = (const float*)d_in[13];
    const float* fc2bb = (const float*)d_in[14];
    const float* fc3w  = (const float*)d_in[15];
    const float* fc3b  = (const float*)d_in[16];
    float* out = (float*)d_out;

    // ---- workspace layout ----
    char* p = (char*)d_ws;
    int* pcnt = (int*)p;                  p += 2048;
    int* pbase = (int*)p;                 p += 2048;
    int* pcur = (int*)p;                  p += 2048;
    int* rowptr = (int*)p;                p += (size_t)(NN + 4) * 4;
    float* dinv = (float*)p;              p += (size_t)NN * 4;
    int* temp = (int*)p;                  p += (size_t)NE * 4;      // 12.8 MB
    int* csr_src = (int*)p;               p += (size_t)NE * 4;      // 12.8 MB
    uint* tb = (uint*)p;                  p += (size_t)NN * 16 * 4; // 6.4 MB bf16 t
    float* x1 = (float*)p;                p += (size_t)NN * 32 * 4;
    float* x2 = (float*)p;                p += (size_t)NN * 32 * 4;
    float* x3 = (float*)p;                p += (size_t)NN * 32 * 4;
    float* pooled = (float*)p;            p += (size_t)NG * 128 * 4;
    float* h64 = (float*)temp;            // alias temp+csr_src (25.6 MB, dead after layer 3)

    const int thr = 256;
    int gN  = (NN + thr - 1) / thr;
    int gTile = (NN + 63) / 64;
    int gGather = (NN * 32 + thr - 1) / thr;
    int gEdge = (NE + CHUNK - 1) / CHUNK;

    // ---- CSR build: all per-edge atomics in LDS ----
    zero_misc_kernel<<<(NG * 128 + thr - 1) / thr, thr, 0, stream>>>(pcnt, pooled);
    phist_kernel<<<gEdge, thr, 0, stream>>>(dstI, pcnt, NE);
    scanP_kernel<<<1, 512, 0, stream>>>(pcnt, pbase, pcur);
    part1_kernel<<<gEdge, thr, 0, stream>>>(srcI, dstI, pcur, temp, NE);
    part2_kernel<<<NPART, thr, 0, stream>>>(temp, pbase, rowptr, dinv, csr_src, NN);

    // ---- conv layers: transform (bf16 out) -> pull gather ----
    gemm128_32_tiled<<<gTile, thr, 0, stream>>>(x, W1, tb, NN);
    gather_bf16_kernel<<<gGather, thr, 0, stream>>>(rowptr, csr_src, dinv, tb, b1, x1, NN);

    gemm32_32_kernel<<<gN, thr, 0, stream>>>(x1, W2, tb, NN);
    gather_bf16_kernel<<<gGather, thr, 0, stream>>>(rowptr, csr_src, dinv, tb, b2, x2, NN);

    gemm32_32_kernel<<<gN, thr, 0, stream>>>(x2, W3w, tb, NN);
    gather_bf16_kernel<<<gGather, thr, 0, stream>>>(rowptr, csr_src, dinv, tb, b3w, x3, NN);

    // ---- MLP head ----
    fc1_tiled_kernel<<<gTile, thr, 0, stream>>>(x1, x2, x3, fc1w, fc1b, h64, NN);
    fc2a_pool_kernel<<<gTile, thr, 0, stream>>>(h64, fc2aw, fc2ab, batch, pooled, NN);

    // ---- classifier ----
    head_kernel<<<(NG + thr - 1) / thr, thr, 0, stream>>>(pooled, fc2bw, fc2bb, fc3w, fc3b, out);
    (void)ws_size; (void)in_sizes; (void)n_in; (void)out_size;
}